// Round 6
// baseline (393.151 us; speedup 1.0000x reference)
//
#include <hip/hip_runtime.h>
#include <math.h>

#define NCLS 19
#define HW   (512*1024)          // 524288
#define CHW  (NCLS*HW)
#define TPIX (2*HW)              // 1048576
#define NB   8192
#define CAND_MAX 4096

// ---- workspace layout (bytes) ----
#define WS_HIST   0                          // NCLS*NB*4 = 622592
#define WS_CANDC  622592                     // NCLS*4 candidate counters
#define WS_ACCUM  622720                     // [0]=sum_loss f32, [1]=cnt_mask u32, [2]=cnt_solid u32
#define WS_TICKET 622736                     // u32 block-completion ticket for fused K5/K6
#define WS_ZERO   622848                     // memset range [0, WS_ZERO)
#define WS_SEL    622848                     // NCLS * {int bin, int rank}
#define WS_NEWTH  623360                     // NCLS*4
#define WS_CONF   623616                     // TPIX*4
#define WS_LOSS   4817920                    // TPIX*4
#define WS_LABEL  9012224                    // TPIX*1
#define WS_CAND   10060800                   // NCLS*CAND_MAX*4 -> end 10372096

// ---------------- K1: block-tiled streaming softmax ----------------
// R1-R5 lesson: per-pixel channel gather = 76 concurrent 2MB-strided streams
// per wave, 256-512B per stream visit -> memory system delivers ~0.9 TB/s no
// matter how many requests are in flight (R4 proved MLP doesn't help).
// Restructure the TRAFFIC: each wave owns a contiguous 256-px slice, loops
// channels with double-buffered width-16 global_load_lds (1KB burst per array
// per channel), wave-local vmcnt gating, zero __syncthreads. Long sequential
// bursts per stream -> page/row locality restored.
#define TILE 1024                 // pixels per block
#define SLICE 256                 // pixels per wave (4 waves/block)

#define GL2LDS(gp, lp) __builtin_amdgcn_global_load_lds( \
    (__attribute__((address_space(1))) void*)(gp),       \
    (__attribute__((address_space(3))) void*)(lp), 16, 0, 0)

__global__ __launch_bounds__(256)
void k1_pixel(const float* __restrict__ lb_t, const float* __restrict__ la_t,
              float4* __restrict__ conf_o, float4* __restrict__ loss_o,
              unsigned int* __restrict__ label_o, unsigned int* __restrict__ hist)
{
    __shared__ float4 sb[2][4][SLICE/4];      // 8 KB: double-buffered b-chunks
    __shared__ float4 sa[2][4][SLICE/4];      // 8 KB: double-buffered a-chunks

    const int l = threadIdx.x & 63;
    const int w = threadIdx.x >> 6;
    const int n        = blockIdx.x >> 9;             // 512 tiles per image
    const int rem_base = (blockIdx.x & 511) * TILE + w * SLICE;
    const float* lb = lb_t + (size_t)n * CHW + rem_base;   // wave's slice, channel 0
    const float* la = la_t + (size_t)n * CHW + rem_base;

    // prologue: DMA chunks 0 and 1 (each: 64 lanes x 16B = 1KB = whole slice)
    GL2LDS(lb + l * 4,      &sb[0][w][0]);
    GL2LDS(la + l * 4,      &sa[0][w][0]);
    GL2LDS(lb + HW + l * 4, &sb[1][w][0]);
    GL2LDS(la + HW + l * 4, &sa[1][w][0]);
    asm volatile("s_waitcnt vmcnt(2)" ::: "memory");  // chunk 0 landed

    float mb[4], zb[4], dot[4], alab[4], ma[4], za[4];
    int lab[4];
    {
        float4 bv = sb[0][w][l];
        float4 av = sa[0][w][l];
        float bb[4] = {bv.x, bv.y, bv.z, bv.w};
        float aa[4] = {av.x, av.y, av.z, av.w};
#pragma unroll
        for (int i = 0; i < 4; ++i) {
            mb[i] = bb[i]; zb[i] = 1.0f; dot[i] = aa[i];
            lab[i] = 0; alab[i] = aa[i]; ma[i] = aa[i]; za[i] = 1.0f;
        }
    }

#pragma unroll
    for (int c = 1; c < NCLS; ++c) {
        if (c + 1 < NCLS) {                            // prefetch c+1
            int par = (c + 1) & 1;
            GL2LDS(lb + (size_t)(c + 1) * HW + l * 4, &sb[par][w][0]);
            GL2LDS(la + (size_t)(c + 1) * HW + l * 4, &sa[par][w][0]);
            asm volatile("s_waitcnt vmcnt(2)" ::: "memory");  // chunk c landed
        } else {
            asm volatile("s_waitcnt vmcnt(0)" ::: "memory");
        }
        int cur = c & 1;
        float4 bv = sb[cur][w][l];
        float4 av = sa[cur][w][l];
        float bb[4] = {bv.x, bv.y, bv.z, bv.w};
        float aa[4] = {av.x, av.y, av.z, av.w};
#pragma unroll
        for (int i = 0; i < 4; ++i) {
            // before-softmax online (max, Z, dot(pb_unnorm, la))
            float mn = fmaxf(mb[i], bb[i]);
            float eo = __expf(mb[i] - mn);
            float en = __expf(bb[i] - mn);
            zb[i]  = zb[i] * eo + en;
            dot[i] = dot[i] * eo + en * aa[i];
            bool upd = bb[i] > mb[i];                  // first-max-wins (strict >)
            lab[i]  = upd ? c : lab[i];
            alab[i] = upd ? aa[i] : alab[i];
            mb[i] = mn;
            // after-softmax online (max, Z)
            float mna = fmaxf(ma[i], aa[i]);
            za[i] = za[i] * __expf(ma[i] - mna) + __expf(aa[i] - mna);
            ma[i] = mna;
        }
    }

    float cf[4], ls[4];
#pragma unroll
    for (int i = 0; i < 4; ++i) {
        cf[i] = 1.0f / zb[i];                          // max softmax prob
        float pa_lab = __expf(alab[i] - ma[i]) / za[i];
        ls[i] = (1.0f - pa_lab) * (ma[i] + __logf(za[i]) - dot[i] / zb[i]);
    }

    int pix0 = n * HW + rem_base + l * 4;              // thread's first pixel
    conf_o[pix0 >> 2] = make_float4(cf[0], cf[1], cf[2], cf[3]);
    loss_o[pix0 >> 2] = make_float4(ls[0], ls[1], ls[2], ls[3]);
    label_o[pix0 >> 2] = (unsigned)lab[0] | ((unsigned)lab[1] << 8) |
                         ((unsigned)lab[2] << 16) | ((unsigned)lab[3] << 24);

#pragma unroll
    for (int i = 0; i < 4; ++i) {
        int bin = (int)(cf[i] * (float)NB);
        bin = bin < (NB - 1) ? bin : (NB - 1);
        atomicAdd(&hist[lab[i] * NB + bin], 1u);
    }
}

// ---------------- K2: per-class rank -> (bin, rank-in-bin) ----------------
__global__ __launch_bounds__(256)
void k2_select(const unsigned int* __restrict__ hist, const float* __restrict__ cls_thresh,
               int* __restrict__ sel, unsigned int* __restrict__ cand_cnt,
               float* __restrict__ cand)
{
    int c = blockIdx.x;
    int t = threadIdx.x;
    float thr = cls_thresh[c];
    int thr_bin = (int)(thr * (float)NB); thr_bin = thr_bin < (NB-1) ? thr_bin : (NB-1);

    __shared__ unsigned hh[NB];                    // 32 KB, coalesced staging
    for (int i = t; i < NB; i += 256) hh[i] = hist[c * NB + i];
    __syncthreads();

    // thread t owns DESCENDING chunk of 32 bins: [NB-(t+1)*32, NB-t*32)
    int base = NB - (t + 1) * 32;
    unsigned s = 0;
    for (int i = 0; i < 32; ++i) {
        unsigned h = hh[base + i];
        if (base + i == thr_bin) h += 1u;          // extended multiset: append thr
        s += h;
    }
    __shared__ unsigned sc[256];
    sc[t] = s;
    __syncthreads();
    for (int off = 1; off < 256; off <<= 1) {
        unsigned vt = sc[t];
        unsigned vp = (t >= off) ? sc[t - off] : 0u;
        __syncthreads();
        sc[t] = vt + vp;
        __syncthreads();
    }
    unsigned total_ext = sc[255];                  // count_c + 1
    unsigned cnt = total_ext - 1u;
    int idx = (int)floorf((float)(cnt + 1u) * 0.2f * powf(thr, 8.0f));

    unsigned above = sc[t] - s;                    // strictly above this chunk
    if ((unsigned)idx >= above && (unsigned)idx < above + s) {
        unsigned cum = above;
        int B = thr_bin, r = 0;
        for (int i = 31; i >= 0; --i) {
            int bi = base + i;
            unsigned h = hh[bi];
            if (bi == thr_bin) h += 1u;
            if ((unsigned)idx < cum + h) { B = bi; r = (int)((unsigned)idx - cum); break; }
            cum += h;
        }
        sel[2 * c]     = B;
        sel[2 * c + 1] = r;
        if (B == thr_bin) {                        // the appended thr is a candidate
            unsigned pos = atomicAdd(&cand_cnt[c], 1u);
            if (pos < CAND_MAX) cand[c * CAND_MAX + pos] = thr;
        }
    }
}

// ---------------- K3: gather candidates in selection bin (4 px/thread) ----------------
__global__ __launch_bounds__(256)
void k3_gather(const float4* __restrict__ conf, const uchar4* __restrict__ label,
               const int* __restrict__ sel, unsigned int* __restrict__ cand_cnt,
               float* __restrict__ cand)
{
    int g = blockIdx.x * 256 + threadIdx.x;
    float4 c4 = conf[g];
    uchar4 l4 = label[g];
    float cf[4] = {c4.x, c4.y, c4.z, c4.w};
    int   lb[4] = {l4.x, l4.y, l4.z, l4.w};
#pragma unroll
    for (int i = 0; i < 4; ++i) {
        int bin = (int)(cf[i] * (float)NB);
        bin = bin < (NB - 1) ? bin : (NB - 1);
        if (bin == sel[2 * lb[i]]) {
            unsigned pos = atomicAdd(&cand_cnt[lb[i]], 1u);
            if (pos < CAND_MAX) cand[lb[i] * CAND_MAX + pos] = cf[i];
        }
    }
}

// ---------------- K4: exact rank among candidates -> new_thresh ----------------
__global__ __launch_bounds__(256)
void k4_thresh(const int* __restrict__ sel, const unsigned int* __restrict__ cand_cnt,
               const float* __restrict__ cand, const float* __restrict__ cls_thresh,
               float* __restrict__ newth)
{
    int c = blockIdx.x;
    int t = threadIdx.x;
    unsigned mc = cand_cnt[c];
    int m = (int)(mc < (unsigned)CAND_MAX ? mc : (unsigned)CAND_MAX);
    int r = sel[2 * c + 1];

    __shared__ float v[CAND_MAX];
    __shared__ float result;
    for (int i = t; i < m; i += 256) v[i] = cand[c * CAND_MAX + i];
    __syncthreads();

    for (int i = t; i < m; i += 256) {
        float x = v[i];
        int gcnt = 0, e = 0;
        for (int j = 0; j < m; ++j) {
            gcnt += (v[j] > x);
            e    += (v[j] == x);
        }
        if (gcnt <= r && r < gcnt + e) result = x;   // duplicates write same value
    }
    __syncthreads();
    if (t == 0) {
        float thr = cls_thresh[c];
        float nt = 0.9f * thr + 0.1f * result;
        if (nt >= 1.0f) nt = 0.999f;
        newth[c] = nt;
    }
}

// ---------------- K5: masked reduction (4 px/thread) + fused output write ----------------
__global__ __launch_bounds__(256)
void k5_reduce(const float4* __restrict__ conf, const float4* __restrict__ loss,
               const uchar4* __restrict__ label, const float* __restrict__ newth,
               float* __restrict__ accum, unsigned int* __restrict__ ticket,
               float* __restrict__ out)
{
    __shared__ float th[NCLS];
    if (threadIdx.x < NCLS) th[threadIdx.x] = newth[threadIdx.x];
    __syncthreads();

    int g = blockIdx.x * 256 + threadIdx.x;
    float4 c4 = conf[g];
    float4 s4 = loss[g];
    uchar4 l4 = label[g];
    float cf[4] = {c4.x, c4.y, c4.z, c4.w};
    float lv[4] = {s4.x, s4.y, s4.z, s4.w};
    int   lb[4] = {l4.x, l4.y, l4.z, l4.w};

    float ls = 0.0f; int mask = 0, solid = 0;
#pragma unroll
    for (int i = 0; i < 4; ++i) {
        bool m = cf[i] > th[lb[i]];
        mask  += m ? 1 : 0;
        solid += (cf[i] > 0.8f) ? 1 : 0;
        ls    += m ? fmaxf(lv[i], 1e-8f) : 0.0f;
    }

    for (int off = 32; off > 0; off >>= 1) {
        ls    += __shfl_down(ls, off, 64);
        mask  += __shfl_down(mask, off, 64);
        solid += __shfl_down(solid, off, 64);
    }
    __shared__ float s_ls[4];
    __shared__ int   s_m[4], s_s[4];
    int w = threadIdx.x >> 6;
    if ((threadIdx.x & 63) == 0) { s_ls[w] = ls; s_m[w] = mask; s_s[w] = solid; }
    __syncthreads();

    __shared__ unsigned done_rank;
    if (threadIdx.x == 0) {
        float L = s_ls[0] + s_ls[1] + s_ls[2] + s_ls[3];
        int   M = s_m[0] + s_m[1] + s_m[2] + s_m[3];
        int   S = s_s[0] + s_s[1] + s_s[2] + s_s[3];
        atomicAdd(&accum[0], L);
        atomicAdd(&((unsigned int*)accum)[1], (unsigned)M);
        atomicAdd(&((unsigned int*)accum)[2], (unsigned)S);
        __threadfence();
        done_rank = atomicAdd(ticket, 1u);
    }
    __syncthreads();
    if (done_rank == gridDim.x - 1 && threadIdx.x == 0) {   // last block writes outputs
        __threadfence();
        float    sum = atomicAdd(&accum[0], 0.0f);
        unsigned cm  = atomicAdd(&((unsigned int*)accum)[1], 0u);
        unsigned cs  = atomicAdd(&((unsigned int*)accum)[2], 0u);
        float den = fmaxf((float)cm, 1.0f);
        out[0] = sum / den;
        out[1] = (float)cm / (float)TPIX;
        out[2] = (float)cs / (float)TPIX;
    }
}

extern "C" void kernel_launch(void* const* d_in, const int* in_sizes, int n_in,
                              void* d_out, int out_size, void* d_ws, size_t ws_size,
                              hipStream_t stream)
{
    const float* lb  = (const float*)d_in[0];
    const float* la  = (const float*)d_in[1];
    const float* cth = (const float*)d_in[2];
    float* out = (float*)d_out;

    char* ws = (char*)d_ws;
    unsigned int* hist     = (unsigned int*)(ws + WS_HIST);
    unsigned int* cand_cnt = (unsigned int*)(ws + WS_CANDC);
    float*        accum    = (float*)(ws + WS_ACCUM);
    unsigned int* ticket   = (unsigned int*)(ws + WS_TICKET);
    int*          sel      = (int*)(ws + WS_SEL);
    float*        newth    = (float*)(ws + WS_NEWTH);
    float*        conf     = (float*)(ws + WS_CONF);
    float*        loss     = (float*)(ws + WS_LOSS);
    unsigned char* label   = (unsigned char*)(ws + WS_LABEL);
    float*        cand     = (float*)(ws + WS_CAND);

    hipMemsetAsync(ws, 0, WS_ZERO, stream);

    dim3 blk(256);
    dim3 grd1(TPIX / TILE);              // 1024 blocks, wave-sliced streaming
    dim3 grd4(TPIX / 4 / 256);           // 1024 blocks, 4 px/thread

    k1_pixel<<<grd1, blk, 0, stream>>>(lb, la, (float4*)conf, (float4*)loss,
                                       (unsigned int*)label, hist);
    k2_select<<<NCLS, blk, 0, stream>>>(hist, cth, sel, cand_cnt, cand);
    k3_gather<<<grd4, blk, 0, stream>>>((const float4*)conf, (const uchar4*)label,
                                        sel, cand_cnt, cand);
    k4_thresh<<<NCLS, blk, 0, stream>>>(sel, cand_cnt, cand, cth, newth);
    k5_reduce<<<grd4, blk, 0, stream>>>((const float4*)conf, (const float4*)loss,
                                        (const uchar4*)label, newth, accum, ticket, out);
}

// Round 7
// 372.234 us; speedup vs baseline: 1.0562x; 1.0562x over previous
//
#include <hip/hip_runtime.h>
#include <math.h>

#define NCLS 19
#define HW   (512*1024)          // 524288
#define CHW  (NCLS*HW)
#define TPIX (2*HW)              // 1048576
#define NB   8192
#define CAND_MAX 4096
#define SUBB 1024                // K4 sub-bins within one conf bin
#define WCAP 1024                // K4 final-candidate capacity

// ---- workspace layout (bytes) ----
#define WS_HIST   0                          // NCLS*NB*4 = 622592
#define WS_CANDC  622592                     // NCLS*4 candidate counters
#define WS_ACCUM  622720                     // [0]=sum_loss f32, [1]=cnt_mask u32, [2]=cnt_solid u32
#define WS_TICKET 622736                     // u32 block-completion ticket for fused K5 output
#define WS_ZERO   622848                     // memset range [0, WS_ZERO)
#define WS_SEL    622848                     // NCLS * {int bin, int rank}
#define WS_NEWTH  623360                     // NCLS*4
#define WS_CONF   623616                     // TPIX*4
#define WS_LOSS   4817920                    // TPIX*4
#define WS_LABEL  9012224                    // TPIX*1
#define WS_CAND   10060800                   // NCLS*CAND_MAX*4 -> end 10372096

// ---------------- K1: per-pixel softmax stats (R1 form — best of 6 variants) ----------------
// R1-R6: scalar, float4, reg-prefetch, LDS-DMA, sched-barrier, burst-dbuf all
// land 188-236 us (~0.9 TB/s) for this 19-stream 2MB-strided gather; MLP and
// burst shaping don't move it. Keep the simplest/fastest (R1: 190 us, VGPR 32).
__global__ __launch_bounds__(256)
void k1_pixel(const float* __restrict__ lb_t, const float* __restrict__ la_t,
              float* __restrict__ conf_o, float* __restrict__ loss_o,
              unsigned char* __restrict__ label_o, unsigned int* __restrict__ hist)
{
    int p = blockIdx.x * 256 + threadIdx.x;      // grid covers TPIX exactly
    int n   = p >> 19;                            // p / HW (HW = 2^19)
    int rem = p & (HW - 1);
    const float* lb = lb_t + (size_t)n * CHW + rem;
    const float* la = la_t + (size_t)n * CHW + rem;

    float b[NCLS], a[NCLS];
#pragma unroll
    for (int c = 0; c < NCLS; ++c) {
        b[c] = lb[(size_t)c * HW];
        a[c] = la[(size_t)c * HW];
    }

    // argmax / max of logits_before (argmax(pb) == argmax(lb)); first-max wins
    float mb = b[0]; int lab = 0;
#pragma unroll
    for (int c = 1; c < NCLS; ++c) { if (b[c] > mb) { mb = b[c]; lab = c; } }
    float ma = a[0];
#pragma unroll
    for (int c = 1; c < NCLS; ++c) ma = fmaxf(ma, a[c]);

    float zb = 0.f, za = 0.f, dot = 0.f;
#pragma unroll
    for (int c = 0; c < NCLS; ++c) {
        float eb = __expf(b[c] - mb);
        zb  += eb;
        dot += eb * a[c];
        za  += __expf(a[c] - ma);
    }
    float conf = 1.0f / zb;                    // exp(0)/zb at argmax channel

    float a_lab = a[0];
#pragma unroll
    for (int c = 1; c < NCLS; ++c) a_lab = (c == lab) ? a[c] : a_lab;
    float pa_lab = __expf(a_lab - ma) / za;

    // loss = (1 - pa_lab) * (ma + log za - dot(pb, la))
    float loss = (1.0f - pa_lab) * (ma + __logf(za) - dot / zb);

    conf_o[p]  = conf;
    loss_o[p]  = loss;
    label_o[p] = (unsigned char)lab;

    int bin = (int)(conf * (float)NB);
    bin = bin < (NB - 1) ? bin : (NB - 1);
    atomicAdd(&hist[lab * NB + bin], 1u);
}

// ---------------- K2: per-class rank -> (bin, rank-in-bin) ----------------
__global__ __launch_bounds__(256)
void k2_select(const unsigned int* __restrict__ hist, const float* __restrict__ cls_thresh,
               int* __restrict__ sel, unsigned int* __restrict__ cand_cnt,
               float* __restrict__ cand)
{
    int c = blockIdx.x;
    int t = threadIdx.x;
    float thr = cls_thresh[c];
    int thr_bin = (int)(thr * (float)NB); thr_bin = thr_bin < (NB-1) ? thr_bin : (NB-1);

    __shared__ unsigned hh[NB];                    // 32 KB, coalesced staging
    for (int i = t; i < NB; i += 256) hh[i] = hist[c * NB + i];
    __syncthreads();

    // thread t owns DESCENDING chunk of 32 bins: [NB-(t+1)*32, NB-t*32)
    int base = NB - (t + 1) * 32;
    unsigned s = 0;
    for (int i = 0; i < 32; ++i) {
        unsigned h = hh[base + i];
        if (base + i == thr_bin) h += 1u;          // extended multiset: append thr
        s += h;
    }
    __shared__ unsigned sc[256];
    sc[t] = s;
    __syncthreads();
    for (int off = 1; off < 256; off <<= 1) {
        unsigned vt = sc[t];
        unsigned vp = (t >= off) ? sc[t - off] : 0u;
        __syncthreads();
        sc[t] = vt + vp;
        __syncthreads();
    }
    unsigned total_ext = sc[255];                  // count_c + 1
    unsigned cnt = total_ext - 1u;
    int idx = (int)floorf((float)(cnt + 1u) * 0.2f * powf(thr, 8.0f));

    unsigned above = sc[t] - s;                    // strictly above this chunk
    if ((unsigned)idx >= above && (unsigned)idx < above + s) {
        unsigned cum = above;
        int B = thr_bin, r = 0;
        for (int i = 31; i >= 0; --i) {
            int bi = base + i;
            unsigned h = hh[bi];
            if (bi == thr_bin) h += 1u;
            if ((unsigned)idx < cum + h) { B = bi; r = (int)((unsigned)idx - cum); break; }
            cum += h;
        }
        sel[2 * c]     = B;
        sel[2 * c + 1] = r;
        if (B == thr_bin) {                        // the appended thr is a candidate
            unsigned pos = atomicAdd(&cand_cnt[c], 1u);
            if (pos < CAND_MAX) cand[c * CAND_MAX + pos] = thr;
        }
    }
}

// ---------------- K3: gather candidates in selection bin (4 px/thread) ----------------
__global__ __launch_bounds__(256)
void k3_gather(const float4* __restrict__ conf, const uchar4* __restrict__ label,
               const int* __restrict__ sel, unsigned int* __restrict__ cand_cnt,
               float* __restrict__ cand)
{
    int g = blockIdx.x * 256 + threadIdx.x;
    float4 c4 = conf[g];
    uchar4 l4 = label[g];
    float cf[4] = {c4.x, c4.y, c4.z, c4.w};
    int   lb[4] = {l4.x, l4.y, l4.z, l4.w};
#pragma unroll
    for (int i = 0; i < 4; ++i) {
        int bin = (int)(cf[i] * (float)NB);
        bin = bin < (NB - 1) ? bin : (NB - 1);
        if (bin == sel[2 * lb[i]]) {
            unsigned pos = atomicAdd(&cand_cnt[lb[i]], 1u);
            if (pos < CAND_MAX) cand[lb[i] * CAND_MAX + pos] = cf[i];
        }
    }
}

// ---------------- K4: rank among candidates via sub-bin histogram, O(m) ----------------
// R1-R6 bug found by budget accounting: the old O(m^2) LDS scan at m~4096 was
// ~65k dependent ds_reads/thread ~= 160 us — the hidden half of total time.
// Refine: 1024 sub-bins over the 1/8192-wide conf bin (exact fp32 mapping:
// lo = B*2^-13 exact, scale 2^23), scan descending, then O(k^2) on the tiny
// sub-bin population only.
__global__ __launch_bounds__(256)
void k4_thresh(const int* __restrict__ sel, const unsigned int* __restrict__ cand_cnt,
               const float* __restrict__ cand, const float* __restrict__ cls_thresh,
               float* __restrict__ newth)
{
    int c = blockIdx.x;
    int t = threadIdx.x;
    unsigned mc = cand_cnt[c];
    int m = (int)(mc < (unsigned)CAND_MAX ? mc : (unsigned)CAND_MAX);
    int r = sel[2 * c + 1];
    int B = sel[2 * c];
    float lo = (float)B * (1.0f / 8192.0f);          // exact: B*2^-13

    __shared__ float    v[CAND_MAX];                  // 16 KB
    __shared__ unsigned h[SUBB];                      // 4 KB
    __shared__ unsigned sc[256];
    __shared__ float    w[WCAP];                      // 4 KB
    __shared__ unsigned wk;
    __shared__ int      selS, selR;
    __shared__ float    result;

    for (int i = t; i < SUBB; i += 256) h[i] = 0u;
    if (t == 0) wk = 0u;
    __syncthreads();

    for (int i = t; i < m; i += 256) {
        float x = cand[c * CAND_MAX + i];
        v[i] = x;
        int s = (int)((x - lo) * 8388608.0f);         // *2^23 -> [0,1024)
        s = s < 0 ? 0 : (s > SUBB - 1 ? SUBB - 1 : s);
        atomicAdd(&h[s], 1u);
    }
    __syncthreads();

    // descending scan: thread t owns sub-bins [SUBB-(t+1)*4, SUBB-t*4)
    int base = SUBB - (t + 1) * 4;
    unsigned s_ = h[base] + h[base + 1] + h[base + 2] + h[base + 3];
    sc[t] = s_;
    __syncthreads();
    for (int off = 1; off < 256; off <<= 1) {
        unsigned vt = sc[t];
        unsigned vp = (t >= off) ? sc[t - off] : 0u;
        __syncthreads();
        sc[t] = vt + vp;
        __syncthreads();
    }
    unsigned above = sc[t] - s_;
    if ((unsigned)r >= above && (unsigned)r < above + s_) {
        unsigned cum = above;
        for (int i = 3; i >= 0; --i) {
            unsigned hh = h[base + i];
            if ((unsigned)r < cum + hh) { selS = base + i; selR = (int)((unsigned)r - cum); break; }
            cum += hh;
        }
    }
    __syncthreads();

    int S = selS, rr = selR;
    for (int i = t; i < m; i += 256) {
        float x = v[i];
        int s = (int)((x - lo) * 8388608.0f);
        s = s < 0 ? 0 : (s > SUBB - 1 ? SUBB - 1 : s);
        if (s == S) {
            unsigned p = atomicAdd(&wk, 1u);
            if (p < WCAP) w[p] = x;
        }
    }
    __syncthreads();

    int k = (int)(wk < (unsigned)WCAP ? wk : (unsigned)WCAP);
    for (int i = t; i < k; i += 256) {
        float x = w[i];
        int g = 0, e = 0;
        for (int j = 0; j < k; ++j) {
            g += (w[j] > x);
            e += (w[j] == x);
        }
        if (g <= rr && rr < g + e) result = x;        // duplicates write same value
    }
    __syncthreads();
    if (t == 0) {
        float thr = cls_thresh[c];
        float nt = 0.9f * thr + 0.1f * result;
        if (nt >= 1.0f) nt = 0.999f;
        newth[c] = nt;
    }
}

// ---------------- K5: masked reduction (4 px/thread) + fused output write ----------------
__global__ __launch_bounds__(256)
void k5_reduce(const float4* __restrict__ conf, const float4* __restrict__ loss,
               const uchar4* __restrict__ label, const float* __restrict__ newth,
               float* __restrict__ accum, unsigned int* __restrict__ ticket,
               float* __restrict__ out)
{
    __shared__ float th[NCLS];
    if (threadIdx.x < NCLS) th[threadIdx.x] = newth[threadIdx.x];
    __syncthreads();

    int g = blockIdx.x * 256 + threadIdx.x;
    float4 c4 = conf[g];
    float4 s4 = loss[g];
    uchar4 l4 = label[g];
    float cf[4] = {c4.x, c4.y, c4.z, c4.w};
    float lv[4] = {s4.x, s4.y, s4.z, s4.w};
    int   lb[4] = {l4.x, l4.y, l4.z, l4.w};

    float ls = 0.0f; int mask = 0, solid = 0;
#pragma unroll
    for (int i = 0; i < 4; ++i) {
        bool m = cf[i] > th[lb[i]];
        mask  += m ? 1 : 0;
        solid += (cf[i] > 0.8f) ? 1 : 0;
        ls    += m ? fmaxf(lv[i], 1e-8f) : 0.0f;
    }

    for (int off = 32; off > 0; off >>= 1) {
        ls    += __shfl_down(ls, off, 64);
        mask  += __shfl_down(mask, off, 64);
        solid += __shfl_down(solid, off, 64);
    }
    __shared__ float s_ls[4];
    __shared__ int   s_m[4], s_s[4];
    int w = threadIdx.x >> 6;
    if ((threadIdx.x & 63) == 0) { s_ls[w] = ls; s_m[w] = mask; s_s[w] = solid; }
    __syncthreads();

    __shared__ unsigned done_rank;
    if (threadIdx.x == 0) {
        float L = s_ls[0] + s_ls[1] + s_ls[2] + s_ls[3];
        int   M = s_m[0] + s_m[1] + s_m[2] + s_m[3];
        int   S = s_s[0] + s_s[1] + s_s[2] + s_s[3];
        atomicAdd(&accum[0], L);
        atomicAdd(&((unsigned int*)accum)[1], (unsigned)M);
        atomicAdd(&((unsigned int*)accum)[2], (unsigned)S);
        __threadfence();
        done_rank = atomicAdd(ticket, 1u);
    }
    __syncthreads();
    if (done_rank == gridDim.x - 1 && threadIdx.x == 0) {   // last block writes outputs
        __threadfence();
        float    sum = atomicAdd(&accum[0], 0.0f);
        unsigned cm  = atomicAdd(&((unsigned int*)accum)[1], 0u);
        unsigned cs  = atomicAdd(&((unsigned int*)accum)[2], 0u);
        float den = fmaxf((float)cm, 1.0f);
        out[0] = sum / den;
        out[1] = (float)cm / (float)TPIX;
        out[2] = (float)cs / (float)TPIX;
    }
}

extern "C" void kernel_launch(void* const* d_in, const int* in_sizes, int n_in,
                              void* d_out, int out_size, void* d_ws, size_t ws_size,
                              hipStream_t stream)
{
    const float* lb  = (const float*)d_in[0];
    const float* la  = (const float*)d_in[1];
    const float* cth = (const float*)d_in[2];
    float* out = (float*)d_out;

    char* ws = (char*)d_ws;
    unsigned int* hist     = (unsigned int*)(ws + WS_HIST);
    unsigned int* cand_cnt = (unsigned int*)(ws + WS_CANDC);
    float*        accum    = (float*)(ws + WS_ACCUM);
    unsigned int* ticket   = (unsigned int*)(ws + WS_TICKET);
    int*          sel      = (int*)(ws + WS_SEL);
    float*        newth    = (float*)(ws + WS_NEWTH);
    float*        conf     = (float*)(ws + WS_CONF);
    float*        loss     = (float*)(ws + WS_LOSS);
    unsigned char* label   = (unsigned char*)(ws + WS_LABEL);
    float*        cand     = (float*)(ws + WS_CAND);

    hipMemsetAsync(ws, 0, WS_ZERO, stream);

    dim3 blk(256);
    dim3 grd1(TPIX / 256);               // 4096 blocks, 1 px/thread
    dim3 grd4(TPIX / 4 / 256);           // 1024 blocks, 4 px/thread

    k1_pixel<<<grd1, blk, 0, stream>>>(lb, la, conf, loss, label, hist);
    k2_select<<<NCLS, blk, 0, stream>>>(hist, cth, sel, cand_cnt, cand);
    k3_gather<<<grd4, blk, 0, stream>>>((const float4*)conf, (const uchar4*)label,
                                        sel, cand_cnt, cand);
    k4_thresh<<<NCLS, blk, 0, stream>>>(sel, cand_cnt, cand, cth, newth);
    k5_reduce<<<grd4, blk, 0, stream>>>((const float4*)conf, (const float4*)loss,
                                        (const uchar4*)label, newth, accum, ticket, out);
}